// Round 4
// baseline (244.669 us; speedup 1.0000x reference)
//
#include <hip/hip_runtime.h>

#define FEAT_H 32
#define FEAT_W 110
#define NCELL (FEAT_H * FEAT_W) /* 3520 */
#define STRIDEPX 16
#define NB 8
#define NG 32
#define NANC 36
#define NC 4
#define A_TOTAL (NCELL * NANC) /* 126720 */

#define SLICES 4                /* colpass cell-slices per column */
#define CPB 512                 /* colpass threads/block */
#define CSLICE (NCELL / SLICES) /* 880 cells per slice */

#define BLK 512              /* k_main: 512 blocks x 512 thr */
#define CHK 512              /* anchors per chunk (= BLK) */
#define NCHK 248             /* ceil(A_TOTAL/CHK); last chunk partial */
#define G2 512
#define CB (G2 / NB)         /* 64 chunk stride per image */
#define MAXSLOTS 4           /* ceil(NCHK/CB) */

__device__ __forceinline__ float smooth_l1(float x) {
    float ax = fabsf(x);
    return ax < 1.f ? 0.5f * ax * ax : ax - 0.5f;
}

// ws: colpart[256*SLICES] u64 @0 (8 KB), acc[8] f32 @8192, done u32 @8224.

// OCCUPANCY MODEL (rounds 2+3 evidence): toolchain budget is
// waves/SIMD x VGPR <= 256. At 128 VGPR only 8 waves/CU fit (round 3:
// doubling the grid left dur EXACTLY unchanged). Round 2 proved the fg
// regression branch can't live in 64 VGPR (168 MB spill). So: fg work is
// deferred to a block-local LDS list + epilogue, cls pipeline is 1-deep,
// and THEN the (BLK,4) cap is safe -> 64 VGPR, 16 waves/CU.
// Tripwire: if WRITE_SIZE >> 10 MB next profile, the cap spilled again.

// Column-max pass, sliced: 4 blocks per (b,g) column, each covering 880 cells.
// Inner argmax tracks a (float,int) pair; u64 packing (iou<<32 | ~a) happens
// once per block, so the downstream merge keeps the exact first-occurrence
// tie rule (max iou, then smallest a).
__global__ __launch_bounds__(CPB) void k_colpass(
    const float* __restrict__ gt_boxes, const int* __restrict__ gt_valid,
    const float* __restrict__ anchors, unsigned long long* __restrict__ colpart,
    float* __restrict__ acc, unsigned* __restrict__ done) {
#pragma clang fp contract(off)
    __shared__ float4 anch4[NANC];
    __shared__ float aarea[NANC];
    __shared__ float wbf[CPB / 64];
    __shared__ int wbi[CPB / 64];
    const int tid = threadIdx.x;
    const int bg = blockIdx.x >> 2; // column (b*NG+g), 0..255
    const int sl = blockIdx.x & 3;  // cell slice, 0..3
    if (blockIdx.x == 0) { // ws is 0xAA-poisoned each call
        if (tid < 8) acc[tid] = 0.f;
        if (tid == 8) *done = 0u;
    }
    if (tid < NANC) {
        const float* ap = anchors + tid * 9;
        const float4 v = make_float4(ap[0], ap[1], ap[2], ap[3]);
        anch4[tid] = v;
        aarea[tid] = (v.z - v.x + 1.f) * (v.w - v.y + 1.f);
    }
    __syncthreads();
    float bf = -1.f;
    int bi = 0;
    if (gt_valid[bg]) {
        const float g0 = gt_boxes[bg * 4 + 0], g1 = gt_boxes[bg * 4 + 1];
        const float g2 = gt_boxes[bg * 4 + 2], g3 = gt_boxes[bg * 4 + 3];
        const float ag = (g2 - g0 + 1.f) * (g3 - g1 + 1.f);
        for (int c = sl * CSLICE + tid; c < (sl + 1) * CSLICE; c += CPB) {
            const float sx = (float)((c % FEAT_W) * STRIDEPX);
            const float sy = (float)((c / FEAT_W) * STRIDEPX);
            int a = c * NANC;
#pragma unroll 4
            for (int t = 0; t < NANC; ++t, ++a) {
                const float4 av = anch4[t];          // wave-uniform broadcast
                const float r0 = sx + av.x, r1 = sy + av.y;
                const float r2 = sx + av.z, r3 = sy + av.w;
                const float xx1 = fmaxf(r0, g0), yy1 = fmaxf(r1, g1);
                const float xx2 = fminf(r2, g2), yy2 = fminf(r3, g3);
                const float iw = fmaxf(xx2 - xx1 + 1.f, 0.f);
                const float ih = fmaxf(yy2 - yy1 + 1.f, 0.f);
                const float inter = iw * ih;
                const float iou =
                    inter * __builtin_amdgcn_rcpf(aarea[t] + ag - inter);
                if (iou > bf) { bf = iou; bi = a; } // strict '>': first occurrence
            }
        }
    }
    for (int off = 32; off; off >>= 1) {
        const float of = __shfl_down(bf, off, 64);
        const int oi = __shfl_down(bi, off, 64);
        if (of > bf || (of == bf && oi < bi)) { bf = of; bi = oi; }
    }
    if ((tid & 63) == 0) { wbf[tid >> 6] = bf; wbi[tid >> 6] = bi; }
    __syncthreads();
    if (tid == 0) {
        for (int w = 1; w < CPB / 64; ++w)
            if (wbf[w] > bf || (wbf[w] == bf && wbi[w] < bi)) {
                bf = wbf[w]; bi = wbi[w];
            }
        const unsigned long long p = (bf < 0.f) ? 0ull :
            (((unsigned long long)__float_as_uint(bf) << 32) |
             (unsigned long long)(0xFFFFFFFFu - (unsigned)bi));
        colpart[bg * SLICES + sl] = p;
    }
}

// Row pass + loss. 512 blocks x 512 threads, b = blk/CB, chunks c0 + k*CB
// (<=4). Slim hot loop (no fg regression, 1-deep cls pipeline) under a
// 64-VGPR cap -> 2 blocks/CU co-resident. fg anchors (rare) are queued in a
// block-local LDS list and regressed in an epilogue with identical per-anchor
// float math.
__global__ __launch_bounds__(BLK, 4) void k_main(
    const float* __restrict__ cls, const float* __restrict__ bbox_2d,
    const float* __restrict__ bbox_3d, const float* __restrict__ gt_boxes,
    const float* __restrict__ gt_3d, const int* __restrict__ gt_labels,
    const int* __restrict__ gt_valid, const float* __restrict__ anchors,
    const float* __restrict__ means, const float* __restrict__ stds,
    const unsigned long long* __restrict__ colpart, float* __restrict__ acc,
    unsigned* __restrict__ done, float* __restrict__ out) {
#pragma clang fp contract(off)
    __shared__ float ax0_s[NANC], ay0_s[NANC], ax1_s[NANC], ay1_s[NANC];
    __shared__ float anch9[NANC * 9];
    __shared__ float4 gtb4_s[NG];
    __shared__ float ags_s[NG];
    __shared__ float gt3_s[NG * 7];
    __shared__ int lbl_s[NG];
    __shared__ int bag_s[NG], forceg_s[NG];
    __shared__ float mean_s[11], rstd_s[11];
    __shared__ unsigned vmask_s;
    __shared__ float red[5][BLK / 64];
    __shared__ int fixmap[MAXSLOTS * BLK];            // 8 KB
    __shared__ unsigned short fglist[MAXSLOTS * BLK]; // 4 KB, hard-bounded
    __shared__ int nloc;

    const int tid = threadIdx.x;
    const int b = blockIdx.x / CB;
    const int c0 = blockIdx.x % CB;

    // ---- staging ----
    for (int i = tid; i < NANC * 9; i += BLK) anch9[i] = anchors[i];
    if (tid < NANC) {
        const float* ap = anchors + tid * 9;
        ax0_s[tid] = ap[0]; ay0_s[tid] = ap[1];
        ax1_s[tid] = ap[2]; ay1_s[tid] = ap[3];
    }
    for (int i = tid; i < NG * 7; i += BLK) gt3_s[i] = gt_3d[b * NG * 7 + i];
    if (tid == 0) nloc = 0;
    int myval = 0;
    if (tid < NG) {
        const float4 q = ((const float4*)gt_boxes)[b * NG + tid];
        gtb4_s[tid] = q;
        ags_s[tid] = (q.z - q.x + 1.f) * (q.w - q.y + 1.f);
        lbl_s[tid] = gt_labels[b * NG + tid];
        myval = gt_valid[b * NG + tid];
        // merge the 4 column slices; packed-max preserves the exact
        // (max iou, then smallest a) first-occurrence rule
        const unsigned long long* cpp = colpart + (b * NG + tid) * SLICES;
        unsigned long long p = cpp[0];
        if (cpp[1] > p) p = cpp[1];
        if (cpp[2] > p) p = cpp[2];
        if (cpp[3] > p) p = cpp[3];
        const float gbest = __uint_as_float((unsigned)(p >> 32));
        bag_s[tid] = myval ? (int)(0xFFFFFFFFu - (unsigned)(p & 0xFFFFFFFFull)) : 0;
        forceg_s[tid] = (myval && gbest >= 0.35f) ? 1 : 0;
    }
    unsigned long long bal = __ballot(tid < NG && myval);
    if (tid == 0) vmask_s = (unsigned)bal;
    if (tid < 11) { mean_s[tid] = means[tid]; rstd_s[tid] = 1.0f / stds[tid]; }
    const int nslots = (NCHK - 1 - c0) / CB + 1; // 4 or 3
    for (int i = tid; i < nslots * BLK; i += BLK) fixmap[i] = -1;
    __syncthreads();
    if (tid == 0) {
        // ascending-g serial build: last-update-wins for agt, OR for force
        // (exact jax .at[ba].set / .at[ba].max gather-before-scatter)
        for (int g = 0; g < NG; ++g) {
            const int ba = bag_s[g];
            const int cb = ba >> 9; // chunk index (CHK=512)
            if (cb % CB == c0) {
                const int k = (cb - c0) / CB;
                const int idx = k * BLK + (ba & (CHK - 1));
                const int e = fixmap[idx];
                const int anyf = ((e >= 0) ? (e & 0x40000000) : 0) |
                                 (forceg_s[g] ? 0x40000000 : 0);
                const int code = forceg_s[g] ? g : 32; // 32 = keep agt_orig
                fixmap[idx] = anyf | code;
            }
        }
    }
    __syncthreads();
    const unsigned vmask = vmask_s;

    // ---- main loop (slim: cls 1-deep pipeline, fg deferred to LDS list) ----
    float sum_ce = 0.f, sum_act = 0.f, sum_fg = 0.f, sum_2d = 0.f, sum_3d = 0.f;
    const size_t bbase = (size_t)b * A_TOTAL;

    int chunk = c0;
    int a0i = chunk * CHK + tid;
    int ae = a0i < A_TOTAL ? a0i : (A_TOTAL - 1);
    float4 cv0 = *(const float4*)(cls + (bbase + ae) * NC);

    for (int k = 0; k < nslots; ++k) {
        float4 cvn = make_float4(0.f, 0.f, 0.f, 0.f);
        if (k + 1 < nslots) {
            int a1i = (chunk + CB) * CHK + tid;
            int ae1 = a1i < A_TOTAL ? a1i : (A_TOTAL - 1);
            cvn = *(const float4*)(cls + (bbase + ae1) * NC);
        }

        const int araw = chunk * CHK + tid;
        const bool live = araw < A_TOTAL;
        const int a = live ? araw : (A_TOTAL - 1); // clamped for safe math
        const int t = a % NANC;
        const int cell = a / NANC;
        const float sx = (float)((cell % FEAT_W) * STRIDEPX);
        const float sy = (float)((cell / FEAT_W) * STRIDEPX);
        const float r0 = sx + ax0_s[t], r1 = sy + ay0_s[t];
        const float r2 = sx + ax1_s[t], r3 = sy + ay1_s[t];
        const float ar = (r2 - r0 + 1.f) * (r3 - r1 + 1.f);

        // grouped argmax: 4 groups of 8, scalar regs; strict '>' ascending
        // preserves first-occurrence exactly (incl. all-invalid -> 0)
        float m0 = -1.f, m1 = -1.f, m2 = -1.f, m3 = -1.f;
        int i0 = 0, i1 = 8, i2 = 16, i3 = 24;
#pragma unroll
        for (int g = 0; g < NG; ++g) {
            const float4 q = gtb4_s[g];              // wave-uniform broadcast
            const float xx1 = fmaxf(r0, q.x), yy1 = fmaxf(r1, q.y);
            const float xx2 = fminf(r2, q.z), yy2 = fminf(r3, q.w);
            const float iw = fmaxf(xx2 - xx1 + 1.f, 0.f);
            const float ih = fmaxf(yy2 - yy1 + 1.f, 0.f);
            const float inter = iw * ih;
            float iou = inter * __builtin_amdgcn_rcpf(ar + ags_s[g] - inter);
            iou = ((vmask >> g) & 1u) ? iou : -1.0f;
            if (g < 8)       { if (iou > m0) { m0 = iou; i0 = g; } }
            else if (g < 16) { if (iou > m1) { m1 = iou; i1 = g; } }
            else if (g < 24) { if (iou > m2) { m2 = iou; i2 = g; } }
            else             { if (iou > m3) { m3 = iou; i3 = g; } }
        }
        float best = m0; int agt = i0;
        if (m1 > best) { best = m1; agt = i1; }
        if (m2 > best) { best = m2; agt = i2; }
        if (m3 > best) { best = m3; agt = i3; }

        bool fg = best >= 0.5f;
        const int agt_orig = agt;
        const int f = fixmap[k * BLK + tid];
        if (f >= 0) {
            if (f & 0x40000000) fg = true;
            const int code = f & 63;
            agt = (code == 32) ? agt_orig : code;
        }
        if (!live) fg = false; // tail lanes contribute nothing
        const bool bgm = live && (!fg) && (best < 0.5f) && (best >= 0.0f);
        const float active = (fg || bgm) ? 1.f : 0.f;
        const int lbl = fg ? lbl_s[agt] : 0;

        const float mx = fmaxf(fmaxf(cv0.x, cv0.y), fmaxf(cv0.z, cv0.w));
        const float se = __expf(cv0.x - mx) + __expf(cv0.y - mx) +
                         __expf(cv0.z - mx) + __expf(cv0.w - mx);
        const float lse = mx + __logf(se);
        const float csel = (lbl == 0) ? cv0.x : (lbl == 1) ? cv0.y
                         : (lbl == 2) ? cv0.z : cv0.w;
        sum_ce += (lse - csel) * active;
        sum_act += active;

        if (fg) { // rare: enqueue {slot,tid,agt}; regression runs in epilogue
            sum_fg += 1.f;
            const int p = atomicAdd(&nloc, 1); // capacity == block anchor count
            fglist[p] = (unsigned short)((k << 14) | (tid << 5) | agt);
        }
        cv0 = cvn;
        chunk += CB;
    }

    // ---- fg regression epilogue (identical per-anchor float math) ----
    __syncthreads(); // all appends visible, nloc final
    const int nfgl = nloc;
    for (int i = tid; i < nfgl; i += BLK) {
        const unsigned e = fglist[i];
        const int k2 = (int)(e >> 14);
        const int tid2 = (int)((e >> 5) & 511u);
        const int agt = (int)(e & 31u);
        const int a = (c0 + k2 * CB) * CHK + tid2;
        const int t = a % NANC;
        const int cell = a / NANC;
        const float sx = (float)((cell % FEAT_W) * STRIDEPX);
        const float sy = (float)((cell / FEAT_W) * STRIDEPX);
        const float r0 = sx + ax0_s[t], r1 = sy + ay0_s[t];
        const float r2 = sx + ax1_s[t], r3 = sy + ay1_s[t];
        const float w = r2 - r0 + 1.f, h = r3 - r1 + 1.f;
        const float rw = __builtin_amdgcn_rcpf(w);
        const float rh = __builtin_amdgcn_rcpf(h);
        const float cx = r0 + 0.5f * w, cy = r1 + 0.5f * h;
        const float4 Gq = gtb4_s[agt];
        const float gw = Gq.z - Gq.x + 1.f, gh = Gq.w - Gq.y + 1.f;
        const float gcx = Gq.x + 0.5f * gw, gcy = Gq.y + 0.5f * gh;
        float tt2[4];
        tt2[0] = (gcx - cx) * rw;
        tt2[1] = (gcy - cy) * rh;
        tt2[2] = __logf(gw * rw);
        tt2[3] = __logf(gh * rh);
        const float4 b2 = *(const float4*)(bbox_2d + (bbase + a) * 4);
        const float b2v[4] = {b2.x, b2.y, b2.z, b2.w};
        float l2 = 0.f;
        for (int j = 0; j < 4; ++j)
            l2 += smooth_l1(b2v[j] - (tt2[j] - mean_s[j]) * rstd_s[j]);
        sum_2d += l2;
        const float* q3p = &gt3_s[agt * 7];
        const float* b3 = bbox_3d + (bbase + a) * 7;
        float tt3[7];
        tt3[0] = (q3p[0] - cx) * rw;
        tt3[1] = (q3p[1] - cy) * rh;
        tt3[2] = q3p[2] - anch9[t * 9 + 4];
        tt3[3] = __logf(q3p[3] * __builtin_amdgcn_rcpf(anch9[t * 9 + 5]));
        tt3[4] = __logf(q3p[4] * __builtin_amdgcn_rcpf(anch9[t * 9 + 6]));
        tt3[5] = __logf(q3p[5] * __builtin_amdgcn_rcpf(anch9[t * 9 + 7]));
        tt3[6] = q3p[6] - anch9[t * 9 + 8];
        float l3 = 0.f;
        for (int j = 0; j < 7; ++j)
            l3 += smooth_l1(b3[j] - (tt3[j] - mean_s[4 + j]) * rstd_s[4 + j]);
        sum_3d += l3;
    }

    // ---- block reduce -> 5 atomics; last block finishes ----
    float vals[5] = {sum_ce, sum_act, sum_fg, sum_2d, sum_3d};
#pragma unroll
    for (int j = 0; j < 5; ++j) {
        float v = vals[j];
        for (int off = 32; off; off >>= 1) v += __shfl_down(v, off, 64);
        if ((tid & 63) == 0) red[j][tid >> 6] = v;
    }
    __syncthreads();
    if (tid == 0) {
        for (int j = 0; j < 5; ++j) {
            float s = 0.f;
            for (int w = 0; w < BLK / 64; ++w) s += red[j][w];
            atomicAdd(&acc[j], s);
        }
        __threadfence();
        const unsigned old = atomicAdd(done, 1u);
        if (old == G2 - 1) {
            const float a0 = atomicAdd(&acc[0], 0.f);
            const float a1 = atomicAdd(&acc[1], 0.f);
            const float a2 = atomicAdd(&acc[2], 0.f);
            const float a3 = atomicAdd(&acc[3], 0.f);
            const float a4 = atomicAdd(&acc[4], 0.f);
            const float nact = fmaxf(a1, 1.f);
            const float nfg = fmaxf(a2, 1.f);
            out[0] = a0 / nact + a3 / nfg + a4 / nfg;
        }
    }
}

extern "C" void kernel_launch(void* const* d_in, const int* in_sizes, int n_in,
                              void* d_out, int out_size, void* d_ws, size_t ws_size,
                              hipStream_t stream) {
    const float* cls      = (const float*)d_in[0];
    const float* bbox_2d  = (const float*)d_in[1];
    const float* bbox_3d  = (const float*)d_in[2];
    const float* gt_boxes = (const float*)d_in[3];
    const float* gt_3d    = (const float*)d_in[4];
    const int*   gt_labels= (const int*)d_in[5];
    const int*   gt_valid = (const int*)d_in[6];
    const float* anchors  = (const float*)d_in[7];
    const float* means    = (const float*)d_in[8];
    const float* stds     = (const float*)d_in[9];

    unsigned long long* colpart = (unsigned long long*)d_ws;  // 8 KB @0
    float* acc = (float*)((char*)d_ws + 8192);
    unsigned* done = (unsigned*)((char*)d_ws + 8192 + 32);
    float* out = (float*)d_out;

    k_colpass<<<NB * NG * SLICES, CPB, 0, stream>>>(gt_boxes, gt_valid, anchors,
                                                    colpart, acc, done);
    k_main<<<G2, BLK, 0, stream>>>(cls, bbox_2d, bbox_3d, gt_boxes, gt_3d,
                                   gt_labels, gt_valid, anchors, means, stds,
                                   colpart, acc, done, out);
}

// Round 5
// 158.201 us; speedup vs baseline: 1.5466x; 1.5466x over previous
//
#include <hip/hip_runtime.h>

#define FEAT_H 32
#define FEAT_W 110
#define NCELL (FEAT_H * FEAT_W) /* 3520 */
#define STRIDEPX 16
#define NB 8
#define NG 32
#define NANC 36
#define NC 4
#define A_TOTAL (NCELL * NANC) /* 126720 */

#define CPB 576              /* colpass: 36 anchor-templates x 16 lanes */

#define BLK 512              /* k_main: 512 blocks x 512 thr */
#define CHK 512              /* anchors per chunk (= BLK) */
#define NCHK 248             /* ceil(A_TOTAL/CHK); last chunk partial */
#define G2 512
#define CB (G2 / NB)         /* 64 chunk stride per image */
#define MAXSLOTS 4           /* ceil(NCHK/CB) */

__device__ __forceinline__ float smooth_l1(float x) {
    float ax = fabsf(x);
    return ax < 1.f ? 0.5f * ax * ax : ax - 0.5f;
}

// ws: colpart[256] u64 @0 (2 KB), acc[8] f32 @8192, done u32 @8224.

// LESSONS (rounds 2-4): (a) never pass a min-waves arg to __launch_bounds__
// here — the VGPR cap it implies (64) spills ~150 MB/dispatch to scratch;
// (b) at VGPR=128 only 8 waves/CU are resident and the k_main inner loop is
// LDS-PIPE-bound (1 ds_read_b128 + 1 ds_read_b32 per g per anchor = 18
// LDS-cyc vs 38 VALU-cyc on 1-of-4 SIMDs -> VALUBusy 30%). Fix: register-
// block 4 anchors per thread so each gtb4/ags LDS read is reused x4.

// Factorized column-max pass: IoU is monotone in inter, and inter(cell) =
// iw(col) * ih(row) is separable. So per (t,g): max over 3520 cells =
// max_col(iw) * max_row(ih), and the first-occurrence argmax is
// (min row of ih-max)*110 + (min col of iw-max) — exact, because the cell
// index is lexicographic (row,col) and iw/ih ties are exact float equalities.
// All float exprs are verbatim from the full-scan version (same fmax/fmin
// order, same rcpf), so the packed (iou<<32 | ~a) is bit-identical.
// Work: 142 evals/(t,g) instead of 3520 -> ~25x less.
__global__ __launch_bounds__(CPB) void k_colpass(
    const float* __restrict__ gt_boxes, const int* __restrict__ gt_valid,
    const float* __restrict__ anchors, unsigned long long* __restrict__ colpart,
    float* __restrict__ acc, unsigned* __restrict__ done) {
#pragma clang fp contract(off)
    __shared__ unsigned long long cand[NANC];
    const int tid = threadIdx.x;
    const int bg = blockIdx.x; // column (b*NG+g), 0..255
    if (bg == 0) { // ws is 0xAA-poisoned each call
        if (tid < 8) acc[tid] = 0.f;
        if (tid == 8) *done = 0u;
    }
    const int t = tid >> 4;    // anchor template 0..35
    const int lane = tid & 15; // 16 lanes per template
    const int valid = gt_valid[bg];
    const float g0 = gt_boxes[bg * 4 + 0], g1 = gt_boxes[bg * 4 + 1];
    const float g2 = gt_boxes[bg * 4 + 2], g3 = gt_boxes[bg * 4 + 3];
    const float ag = (g2 - g0 + 1.f) * (g3 - g1 + 1.f);
    const float* ap = anchors + t * 9;
    const float ax0 = ap[0], ay0 = ap[1], ax1 = ap[2], ay1 = ap[3];
    const float aarea = (ax1 - ax0 + 1.f) * (ay1 - ay0 + 1.f);

    // iw over the 110 columns (ascending per lane -> strict '>' keeps first)
    float iwm = -1.f; int icol = 0;
    for (int col = lane; col < FEAT_W; col += 16) {
        const float sx = (float)(col * STRIDEPX);
        const float r0 = sx + ax0, r2 = sx + ax1;
        const float xx1 = fmaxf(r0, g0), xx2 = fminf(r2, g2);
        const float iw = fmaxf(xx2 - xx1 + 1.f, 0.f);
        if (iw > iwm) { iwm = iw; icol = col; }
    }
    // ih over the 32 rows
    float ihm = -1.f; int irow = 0;
    for (int row = lane; row < FEAT_H; row += 16) {
        const float sy = (float)(row * STRIDEPX);
        const float r1 = sy + ay0, r3 = sy + ay1;
        const float yy1 = fmaxf(r1, g1), yy2 = fminf(r3, g3);
        const float ih = fmaxf(yy2 - yy1 + 1.f, 0.f);
        if (ih > ihm) { ihm = ih; irow = row; }
    }
    // (max, min-index) reduction across the 16-lane group
    for (int off = 8; off; off >>= 1) {
        const float ow = __shfl_down(iwm, off, 16);
        const int oc = __shfl_down(icol, off, 16);
        if (ow > iwm || (ow == iwm && oc < icol)) { iwm = ow; icol = oc; }
        const float oh = __shfl_down(ihm, off, 16);
        const int orw = __shfl_down(irow, off, 16);
        if (oh > ihm || (oh == ihm && orw < irow)) { ihm = oh; irow = orw; }
    }
    if (lane == 0) {
        const float inter = iwm * ihm;                       // verbatim iw*ih
        const float iou = inter * __builtin_amdgcn_rcpf(aarea + ag - inter);
        const int a = (irow * FEAT_W + icol) * NANC + t;
        cand[t] = valid
            ? (((unsigned long long)__float_as_uint(iou) << 32) |
               (unsigned long long)(0xFFFFFFFFu - (unsigned)a))
            : 0ull;
    }
    __syncthreads();
    if (tid == 0) {
        unsigned long long best = cand[0];
        for (int u = 1; u < NANC; ++u)
            if (cand[u] > best) best = cand[u];
        colpart[bg] = best;
    }
}

// Row pass + loss. 512 blocks x 512 threads, b = blk/CB. Each thread owns
// FOUR anchors (slots k=0..3, chunks c0+k*64) simultaneously: the g-loop
// reads gtb4_s[g]/ags_s[g] from LDS ONCE and applies it to all 4 anchors,
// cutting the LDS-pipe load 4x (the round-3 bottleneck). Dead slots
// (araw >= A_TOTAL, incl. nslots==3 blocks) fall out of the live guard.
// fg anchors (rare) are queued to an LDS list and regressed in an epilogue
// (identical per-anchor float math; proven absmax 0.0 in round 4).
__global__ __launch_bounds__(BLK) void k_main(
    const float* __restrict__ cls, const float* __restrict__ bbox_2d,
    const float* __restrict__ bbox_3d, const float* __restrict__ gt_boxes,
    const float* __restrict__ gt_3d, const int* __restrict__ gt_labels,
    const int* __restrict__ gt_valid, const float* __restrict__ anchors,
    const float* __restrict__ means, const float* __restrict__ stds,
    const unsigned long long* __restrict__ colpart, float* __restrict__ acc,
    unsigned* __restrict__ done, float* __restrict__ out) {
#pragma clang fp contract(off)
    __shared__ float ax0_s[NANC], ay0_s[NANC], ax1_s[NANC], ay1_s[NANC];
    __shared__ float anch9[NANC * 9];
    __shared__ float4 gtb4_s[NG];
    __shared__ float ags_s[NG];
    __shared__ float gt3_s[NG * 7];
    __shared__ int lbl_s[NG];
    __shared__ int bag_s[NG], forceg_s[NG];
    __shared__ float mean_s[11], rstd_s[11];
    __shared__ unsigned vmask_s;
    __shared__ float red[5][BLK / 64];
    __shared__ int fixmap[MAXSLOTS * BLK];            // 8 KB
    __shared__ unsigned short fglist[MAXSLOTS * BLK]; // 4 KB, hard-bounded
    __shared__ int nloc;

    const int tid = threadIdx.x;
    const int b = blockIdx.x / CB;
    const int c0 = blockIdx.x % CB;

    // ---- staging ----
    for (int i = tid; i < NANC * 9; i += BLK) anch9[i] = anchors[i];
    if (tid < NANC) {
        const float* ap = anchors + tid * 9;
        ax0_s[tid] = ap[0]; ay0_s[tid] = ap[1];
        ax1_s[tid] = ap[2]; ay1_s[tid] = ap[3];
    }
    for (int i = tid; i < NG * 7; i += BLK) gt3_s[i] = gt_3d[b * NG * 7 + i];
    if (tid == 0) nloc = 0;
    int myval = 0;
    if (tid < NG) {
        const float4 q = ((const float4*)gt_boxes)[b * NG + tid];
        gtb4_s[tid] = q;
        ags_s[tid] = (q.z - q.x + 1.f) * (q.w - q.y + 1.f);
        lbl_s[tid] = gt_labels[b * NG + tid];
        myval = gt_valid[b * NG + tid];
        const unsigned long long p = colpart[b * NG + tid];
        const float gbest = __uint_as_float((unsigned)(p >> 32));
        bag_s[tid] = myval ? (int)(0xFFFFFFFFu - (unsigned)(p & 0xFFFFFFFFull)) : 0;
        forceg_s[tid] = (myval && gbest >= 0.35f) ? 1 : 0;
    }
    unsigned long long bal = __ballot(tid < NG && myval);
    if (tid == 0) vmask_s = (unsigned)bal;
    if (tid < 11) { mean_s[tid] = means[tid]; rstd_s[tid] = 1.0f / stds[tid]; }
    for (int i = tid; i < MAXSLOTS * BLK; i += BLK) fixmap[i] = -1;
    __syncthreads();
    if (tid == 0) {
        // ascending-g serial build: last-update-wins for agt, OR for force
        // (exact jax .at[ba].set / .at[ba].max gather-before-scatter)
        for (int g = 0; g < NG; ++g) {
            const int ba = bag_s[g];
            const int cb = ba >> 9; // chunk index (CHK=512)
            if (cb % CB == c0) {
                const int k = (cb - c0) / CB;
                const int idx = k * BLK + (ba & (CHK - 1));
                const int e = fixmap[idx];
                const int anyf = ((e >= 0) ? (e & 0x40000000) : 0) |
                                 (forceg_s[g] ? 0x40000000 : 0);
                const int code = forceg_s[g] ? g : 32; // 32 = keep agt_orig
                fixmap[idx] = anyf | code;
            }
        }
    }
    __syncthreads();
    const unsigned vmask = vmask_s;
    const size_t bbase = (size_t)b * A_TOTAL;

    // ---- per-slot setup: 4 anchors per thread, all state in registers ----
    int araw[MAXSLOTS];
    float4 cv[MAXSLOTS];
    float r0a[MAXSLOTS], r1a[MAXSLOTS], r2a[MAXSLOTS], r3a[MAXSLOTS];
    float ara[MAXSLOTS];
#pragma unroll
    for (int k = 0; k < MAXSLOTS; ++k) {
        araw[k] = (c0 + k * CB) * CHK + tid;
        const int ae = araw[k] < A_TOTAL ? araw[k] : (A_TOTAL - 1);
        cv[k] = *(const float4*)(cls + (bbase + ae) * NC); // prefetch CE input
        const int t = ae % NANC;
        const int cell = ae / NANC;
        const float sx = (float)((cell % FEAT_W) * STRIDEPX);
        const float sy = (float)((cell / FEAT_W) * STRIDEPX);
        r0a[k] = sx + ax0_s[t]; r1a[k] = sy + ay0_s[t];
        r2a[k] = sx + ax1_s[t]; r3a[k] = sy + ay1_s[t];
        ara[k] = (r2a[k] - r0a[k] + 1.f) * (r3a[k] - r1a[k] + 1.f);
    }

    // ---- IoU + argmax: one LDS read of (gtb4,ags) serves 4 anchors ----
    // single ascending chain with strict '>' = exact first-occurrence argmax
    float m[MAXSLOTS] = {-1.f, -1.f, -1.f, -1.f};
    int iagt[MAXSLOTS] = {0, 0, 0, 0};
#pragma unroll 4
    for (int g = 0; g < NG; ++g) {
        if (!((vmask >> g) & 1u)) continue; // wave-uniform skip == mask to -1
        const float4 q = gtb4_s[g];         // wave-uniform broadcast
        const float agv = ags_s[g];
#pragma unroll
        for (int k = 0; k < MAXSLOTS; ++k) {
            const float xx1 = fmaxf(r0a[k], q.x), yy1 = fmaxf(r1a[k], q.y);
            const float xx2 = fminf(r2a[k], q.z), yy2 = fminf(r3a[k], q.w);
            const float iw = fmaxf(xx2 - xx1 + 1.f, 0.f);
            const float ih = fmaxf(yy2 - yy1 + 1.f, 0.f);
            const float inter = iw * ih;
            const float iou = inter * __builtin_amdgcn_rcpf(ara[k] + agv - inter);
            if (iou > m[k]) { m[k] = iou; iagt[k] = g; }
        }
    }

    // ---- per-slot epilogue: fixmap, CE, fg enqueue ----
    float sum_ce = 0.f, sum_act = 0.f, sum_fg = 0.f, sum_2d = 0.f, sum_3d = 0.f;
#pragma unroll
    for (int k = 0; k < MAXSLOTS; ++k) {
        const bool live = araw[k] < A_TOTAL;
        const float best = m[k];
        int agt = iagt[k];
        bool fg = best >= 0.5f;
        const int f = fixmap[k * BLK + tid];
        if (f >= 0) {
            if (f & 0x40000000) fg = true;
            const int code = f & 63;
            agt = (code == 32) ? agt : code;
        }
        if (!live) fg = false; // dead slots/tail lanes contribute nothing
        const bool bgm = live && (!fg) && (best < 0.5f) && (best >= 0.0f);
        const float active = (fg || bgm) ? 1.f : 0.f;
        const int lbl = fg ? lbl_s[agt] : 0;

        const float4 c4 = cv[k];
        const float mx = fmaxf(fmaxf(c4.x, c4.y), fmaxf(c4.z, c4.w));
        const float se = __expf(c4.x - mx) + __expf(c4.y - mx) +
                         __expf(c4.z - mx) + __expf(c4.w - mx);
        const float lse = mx + __logf(se);
        const float csel = (lbl == 0) ? c4.x : (lbl == 1) ? c4.y
                         : (lbl == 2) ? c4.z : c4.w;
        sum_ce += (lse - csel) * active;
        sum_act += active;

        if (fg) { // rare: enqueue {slot,tid,agt}; regression runs below
            sum_fg += 1.f;
            const int p = atomicAdd(&nloc, 1); // capacity == block anchor count
            fglist[p] = (unsigned short)((k << 14) | (tid << 5) | agt);
        }
    }

    // ---- fg regression epilogue (identical per-anchor float math) ----
    __syncthreads(); // all appends visible, nloc final
    const int nfgl = nloc;
    for (int i = tid; i < nfgl; i += BLK) {
        const unsigned e = fglist[i];
        const int k2 = (int)(e >> 14);
        const int tid2 = (int)((e >> 5) & 511u);
        const int agt = (int)(e & 31u);
        const int a = (c0 + k2 * CB) * CHK + tid2;
        const int t = a % NANC;
        const int cell = a / NANC;
        const float sx = (float)((cell % FEAT_W) * STRIDEPX);
        const float sy = (float)((cell / FEAT_W) * STRIDEPX);
        const float r0 = sx + ax0_s[t], r1 = sy + ay0_s[t];
        const float r2 = sx + ax1_s[t], r3 = sy + ay1_s[t];
        const float w = r2 - r0 + 1.f, h = r3 - r1 + 1.f;
        const float rw = __builtin_amdgcn_rcpf(w);
        const float rh = __builtin_amdgcn_rcpf(h);
        const float cx = r0 + 0.5f * w, cy = r1 + 0.5f * h;
        const float4 Gq = gtb4_s[agt];
        const float gw = Gq.z - Gq.x + 1.f, gh = Gq.w - Gq.y + 1.f;
        const float gcx = Gq.x + 0.5f * gw, gcy = Gq.y + 0.5f * gh;
        float tt2[4];
        tt2[0] = (gcx - cx) * rw;
        tt2[1] = (gcy - cy) * rh;
        tt2[2] = __logf(gw * rw);
        tt2[3] = __logf(gh * rh);
        const float4 b2 = *(const float4*)(bbox_2d + (bbase + a) * 4);
        const float b2v[4] = {b2.x, b2.y, b2.z, b2.w};
        float l2 = 0.f;
        for (int j = 0; j < 4; ++j)
            l2 += smooth_l1(b2v[j] - (tt2[j] - mean_s[j]) * rstd_s[j]);
        sum_2d += l2;
        const float* q3p = &gt3_s[agt * 7];
        const float* b3 = bbox_3d + (bbase + a) * 7;
        float tt3[7];
        tt3[0] = (q3p[0] - cx) * rw;
        tt3[1] = (q3p[1] - cy) * rh;
        tt3[2] = q3p[2] - anch9[t * 9 + 4];
        tt3[3] = __logf(q3p[3] * __builtin_amdgcn_rcpf(anch9[t * 9 + 5]));
        tt3[4] = __logf(q3p[4] * __builtin_amdgcn_rcpf(anch9[t * 9 + 6]));
        tt3[5] = __logf(q3p[5] * __builtin_amdgcn_rcpf(anch9[t * 9 + 7]));
        tt3[6] = q3p[6] - anch9[t * 9 + 8];
        float l3 = 0.f;
        for (int j = 0; j < 7; ++j)
            l3 += smooth_l1(b3[j] - (tt3[j] - mean_s[4 + j]) * rstd_s[4 + j]);
        sum_3d += l3;
    }

    // ---- block reduce -> 5 atomics; last block finishes ----
    float vals[5] = {sum_ce, sum_act, sum_fg, sum_2d, sum_3d};
#pragma unroll
    for (int j = 0; j < 5; ++j) {
        float v = vals[j];
        for (int off = 32; off; off >>= 1) v += __shfl_down(v, off, 64);
        if ((tid & 63) == 0) red[j][tid >> 6] = v;
    }
    __syncthreads();
    if (tid == 0) {
        for (int j = 0; j < 5; ++j) {
            float s = 0.f;
            for (int w = 0; w < BLK / 64; ++w) s += red[j][w];
            atomicAdd(&acc[j], s);
        }
        __threadfence();
        const unsigned old = atomicAdd(done, 1u);
        if (old == G2 - 1) {
            const float a0 = atomicAdd(&acc[0], 0.f);
            const float a1 = atomicAdd(&acc[1], 0.f);
            const float a2 = atomicAdd(&acc[2], 0.f);
            const float a3 = atomicAdd(&acc[3], 0.f);
            const float a4 = atomicAdd(&acc[4], 0.f);
            const float nact = fmaxf(a1, 1.f);
            const float nfg = fmaxf(a2, 1.f);
            out[0] = a0 / nact + a3 / nfg + a4 / nfg;
        }
    }
}

extern "C" void kernel_launch(void* const* d_in, const int* in_sizes, int n_in,
                              void* d_out, int out_size, void* d_ws, size_t ws_size,
                              hipStream_t stream) {
    const float* cls      = (const float*)d_in[0];
    const float* bbox_2d  = (const float*)d_in[1];
    const float* bbox_3d  = (const float*)d_in[2];
    const float* gt_boxes = (const float*)d_in[3];
    const float* gt_3d    = (const float*)d_in[4];
    const int*   gt_labels= (const int*)d_in[5];
    const int*   gt_valid = (const int*)d_in[6];
    const float* anchors  = (const float*)d_in[7];
    const float* means    = (const float*)d_in[8];
    const float* stds     = (const float*)d_in[9];

    unsigned long long* colpart = (unsigned long long*)d_ws;  // 2 KB @0
    float* acc = (float*)((char*)d_ws + 8192);
    unsigned* done = (unsigned*)((char*)d_ws + 8192 + 32);
    float* out = (float*)d_out;

    k_colpass<<<NB * NG, CPB, 0, stream>>>(gt_boxes, gt_valid, anchors,
                                           colpart, acc, done);
    k_main<<<G2, BLK, 0, stream>>>(cls, bbox_2d, bbox_3d, gt_boxes, gt_3d,
                                   gt_labels, gt_valid, anchors, means, stds,
                                   colpart, acc, done, out);
}

// Round 6
// 149.794 us; speedup vs baseline: 1.6334x; 1.0561x over previous
//
#include <hip/hip_runtime.h>

#define FEAT_H 32
#define FEAT_W 110
#define NCELL (FEAT_H * FEAT_W) /* 3520 */
#define STRIDEPX 16
#define NB 8
#define NG 32
#define NANC 36
#define NC 4
#define A_TOTAL (NCELL * NANC) /* 126720 */

#define CPB 576              /* colpass: 36 anchor-templates x 16 lanes */

#define BLK 512              /* k_main: 256 blocks x 512 thr */
#define CHK 512              /* anchors per chunk (= BLK) */
#define NCHK 248             /* ceil(A_TOTAL/CHK); last chunk partial */
#define G2 256
#define CB (G2 / NB)         /* 32 chunk stride per image */
#define MAXSLOTS 8           /* ceil(NCHK/CB) */

__device__ __forceinline__ float smooth_l1(float x) {
    float ax = fabsf(x);
    return ax < 1.f ? 0.5f * ax * ax : ax - 0.5f;
}

// ws: colpart[256] u64 @0 (2 KB), acc[8] f32 @8192, done u32 @8224.

// LESSONS (rounds 2-5):
// (a) never pass a min-waves arg to __launch_bounds__ — the implied VGPR cap
//     spills ~150 MB/dispatch (rounds 2/4).
// (b) r5 counters: total VALU work is only ~19 us at full issue density
//     (VALUBusy 31% x 61 us); the kernel is ISSUE-EFFICIENCY bound, not
//     work bound. Levers: per-thread ILP (8 slots), no LDS in hot loop
//     (wave-uniform s_load of gt_boxes instead), branchless g-loop.
// (c) ~97 us of the e2e time is harness reset machinery (invariant across
//     all rounds); k_main is the only controllable cost.

// Factorized column-max pass (r5, exact): IoU monotone in inter and
// inter = iw(col)*ih(row) separable -> per (t,g) the 3520-cell max is
// max_col(iw)*max_row(ih); first-occurrence argmax = (min row of ih-max,
// min col of iw-max), lexicographic like the cell index. Float exprs
// verbatim -> packed (iou<<32 | ~a) bit-identical to the full scan.
__global__ __launch_bounds__(CPB) void k_colpass(
    const float* __restrict__ gt_boxes, const int* __restrict__ gt_valid,
    const float* __restrict__ anchors, unsigned long long* __restrict__ colpart,
    float* __restrict__ acc, unsigned* __restrict__ done) {
#pragma clang fp contract(off)
    __shared__ unsigned long long cand[NANC];
    const int tid = threadIdx.x;
    const int bg = blockIdx.x; // column (b*NG+g), 0..255
    if (bg == 0) { // ws is 0xAA-poisoned each call
        if (tid < 8) acc[tid] = 0.f;
        if (tid == 8) *done = 0u;
    }
    const int t = tid >> 4;    // anchor template 0..35
    const int lane = tid & 15; // 16 lanes per template
    const int valid = gt_valid[bg];
    const float g0 = gt_boxes[bg * 4 + 0], g1 = gt_boxes[bg * 4 + 1];
    const float g2 = gt_boxes[bg * 4 + 2], g3 = gt_boxes[bg * 4 + 3];
    const float ag = (g2 - g0 + 1.f) * (g3 - g1 + 1.f);
    const float* ap = anchors + t * 9;
    const float ax0 = ap[0], ay0 = ap[1], ax1 = ap[2], ay1 = ap[3];
    const float aarea = (ax1 - ax0 + 1.f) * (ay1 - ay0 + 1.f);

    // iw over the 110 columns (ascending per lane -> strict '>' keeps first)
    float iwm = -1.f; int icol = 0;
    for (int col = lane; col < FEAT_W; col += 16) {
        const float sx = (float)(col * STRIDEPX);
        const float r0 = sx + ax0, r2 = sx + ax1;
        const float xx1 = fmaxf(r0, g0), xx2 = fminf(r2, g2);
        const float iw = fmaxf(xx2 - xx1 + 1.f, 0.f);
        if (iw > iwm) { iwm = iw; icol = col; }
    }
    // ih over the 32 rows
    float ihm = -1.f; int irow = 0;
    for (int row = lane; row < FEAT_H; row += 16) {
        const float sy = (float)(row * STRIDEPX);
        const float r1 = sy + ay0, r3 = sy + ay1;
        const float yy1 = fmaxf(r1, g1), yy2 = fminf(r3, g3);
        const float ih = fmaxf(yy2 - yy1 + 1.f, 0.f);
        if (ih > ihm) { ihm = ih; irow = row; }
    }
    // (max, min-index) reduction across the 16-lane group
    for (int off = 8; off; off >>= 1) {
        const float ow = __shfl_down(iwm, off, 16);
        const int oc = __shfl_down(icol, off, 16);
        if (ow > iwm || (ow == iwm && oc < icol)) { iwm = ow; icol = oc; }
        const float oh = __shfl_down(ihm, off, 16);
        const int orw = __shfl_down(irow, off, 16);
        if (oh > ihm || (oh == ihm && orw < irow)) { ihm = oh; irow = orw; }
    }
    if (lane == 0) {
        const float inter = iwm * ihm;                       // verbatim iw*ih
        const float iou = inter * __builtin_amdgcn_rcpf(aarea + ag - inter);
        const int a = (irow * FEAT_W + icol) * NANC + t;
        cand[t] = valid
            ? (((unsigned long long)__float_as_uint(iou) << 32) |
               (unsigned long long)(0xFFFFFFFFu - (unsigned)a))
            : 0ull;
    }
    __syncthreads();
    if (tid == 0) {
        unsigned long long best = cand[0];
        for (int u = 1; u < NANC; ++u)
            if (cand[u] > best) best = cand[u];
        colpart[bg] = best;
    }
}

// Row pass + loss. 256 blocks x 512 threads (1 block/CU, minimal dispatch
// ramp). Each thread owns EIGHT anchors (slots k=0..7, chunks c0+k*32):
// 8 independent IoU chains per thread feed the VALU back-to-back. The g-loop
// is LDS-free and branchless: gt boxes come from wave-uniform s_loads
// (software-pipelined one g ahead), area recomputed inline (bit-identical
// expr), invalid g masked by cndmask to -1 (round-0-proven semantics).
// cls is loaded in the CE epilogue (keeps main-loop VGPR liveness low);
// fg anchors are queued to an LDS list and regressed in an epilogue
// (identical per-anchor float math; absmax 0.0 proven rounds 4-5).
__global__ __launch_bounds__(BLK) void k_main(
    const float* __restrict__ cls, const float* __restrict__ bbox_2d,
    const float* __restrict__ bbox_3d, const float* __restrict__ gt_boxes,
    const float* __restrict__ gt_3d, const int* __restrict__ gt_labels,
    const int* __restrict__ gt_valid, const float* __restrict__ anchors,
    const float* __restrict__ means, const float* __restrict__ stds,
    const unsigned long long* __restrict__ colpart, float* __restrict__ acc,
    unsigned* __restrict__ done, float* __restrict__ out) {
#pragma clang fp contract(off)
    __shared__ float ax0_s[NANC], ay0_s[NANC], ax1_s[NANC], ay1_s[NANC];
    __shared__ float anch9[NANC * 9];
    __shared__ float4 gtb4_s[NG];     // for epilogue gathers only
    __shared__ float gt3_s[NG * 7];
    __shared__ int lbl_s[NG];
    __shared__ int bag_s[NG], forceg_s[NG];
    __shared__ float mean_s[11], rstd_s[11];
    __shared__ unsigned vmask_s;
    __shared__ float red[5][BLK / 64];
    __shared__ int fixmap[MAXSLOTS * BLK];       // 16 KB
    __shared__ unsigned fglist[MAXSLOTS * BLK];  // 16 KB, hard-bounded
    __shared__ int nloc;

    const int tid = threadIdx.x;
    const int b = blockIdx.x / CB;
    const int c0 = blockIdx.x % CB;

    // ---- staging ----
    for (int i = tid; i < NANC * 9; i += BLK) anch9[i] = anchors[i];
    if (tid < NANC) {
        const float* ap = anchors + tid * 9;
        ax0_s[tid] = ap[0]; ay0_s[tid] = ap[1];
        ax1_s[tid] = ap[2]; ay1_s[tid] = ap[3];
    }
    for (int i = tid; i < NG * 7; i += BLK) gt3_s[i] = gt_3d[b * NG * 7 + i];
    if (tid == 0) nloc = 0;
    int myval = 0;
    if (tid < NG) {
        const float4 q = ((const float4*)gt_boxes)[b * NG + tid];
        gtb4_s[tid] = q;
        lbl_s[tid] = gt_labels[b * NG + tid];
        myval = gt_valid[b * NG + tid];
        const unsigned long long p = colpart[b * NG + tid];
        const float gbest = __uint_as_float((unsigned)(p >> 32));
        bag_s[tid] = myval ? (int)(0xFFFFFFFFu - (unsigned)(p & 0xFFFFFFFFull)) : 0;
        forceg_s[tid] = (myval && gbest >= 0.35f) ? 1 : 0;
    }
    unsigned long long bal = __ballot(tid < NG && myval);
    if (tid == 0) vmask_s = (unsigned)bal;
    if (tid < 11) { mean_s[tid] = means[tid]; rstd_s[tid] = 1.0f / stds[tid]; }
    for (int i = tid; i < MAXSLOTS * BLK; i += BLK) fixmap[i] = -1;
    __syncthreads();
    if (tid == 0) {
        // ascending-g serial build: last-update-wins for agt, OR for force
        // (exact jax .at[ba].set / .at[ba].max gather-before-scatter)
        for (int g = 0; g < NG; ++g) {
            const int ba = bag_s[g];
            const int cb = ba >> 9; // chunk index (CHK=512)
            if (cb % CB == c0) {
                const int k = (cb - c0) / CB;
                const int idx = k * BLK + (ba & (CHK - 1));
                const int e = fixmap[idx];
                const int anyf = ((e >= 0) ? (e & 0x40000000) : 0) |
                                 (forceg_s[g] ? 0x40000000 : 0);
                const int code = forceg_s[g] ? g : 32; // 32 = keep agt_orig
                fixmap[idx] = anyf | code;
            }
        }
    }
    __syncthreads();
    const unsigned vmask = vmask_s;
    const size_t bbase = (size_t)b * A_TOTAL;

    // ---- per-slot setup: 8 anchors per thread, coords in registers ----
    float r0a[MAXSLOTS], r1a[MAXSLOTS], r2a[MAXSLOTS], r3a[MAXSLOTS];
    float ara[MAXSLOTS];
#pragma unroll
    for (int k = 0; k < MAXSLOTS; ++k) {
        const int araw = (c0 + k * CB) * CHK + tid;
        const int ae = araw < A_TOTAL ? araw : (A_TOTAL - 1);
        const int t = ae % NANC;
        const int cell = ae / NANC;
        const float sx = (float)((cell % FEAT_W) * STRIDEPX);
        const float sy = (float)((cell / FEAT_W) * STRIDEPX);
        r0a[k] = sx + ax0_s[t]; r1a[k] = sy + ay0_s[t];
        r2a[k] = sx + ax1_s[t]; r3a[k] = sy + ay1_s[t];
        ara[k] = (r2a[k] - r0a[k] + 1.f) * (r3a[k] - r1a[k] + 1.f);
    }

    // ---- IoU + argmax: LDS-free, branchless, s_load pipelined 1 ahead ----
    // strict '>' ascending chain = exact first-occurrence argmax; invalid g
    // forced to -1 (never beats the -1 init), identical to reference.
    const float4* gtb = (const float4*)gt_boxes + (size_t)b * NG;
    float m[MAXSLOTS];
    int ia[MAXSLOTS];
#pragma unroll
    for (int k = 0; k < MAXSLOTS; ++k) { m[k] = -1.f; ia[k] = 0; }
    float4 qn = gtb[0];
#pragma unroll 4
    for (int g = 0; g < NG; ++g) {
        const float4 q = qn;                  // wave-uniform (SGPR operands)
        if (g + 1 < NG) qn = gtb[g + 1];      // prefetch next g
        const bool gv = (vmask >> g) & 1u;
        const float agv = (q.z - q.x + 1.f) * (q.w - q.y + 1.f);
#pragma unroll
        for (int k = 0; k < MAXSLOTS; ++k) {
            const float xx1 = fmaxf(r0a[k], q.x), yy1 = fmaxf(r1a[k], q.y);
            const float xx2 = fminf(r2a[k], q.z), yy2 = fminf(r3a[k], q.w);
            const float iw = fmaxf(xx2 - xx1 + 1.f, 0.f);
            const float ih = fmaxf(yy2 - yy1 + 1.f, 0.f);
            const float inter = iw * ih;
            float iou = inter * __builtin_amdgcn_rcpf(ara[k] + agv - inter);
            iou = gv ? iou : -1.0f;
            if (iou > m[k]) { m[k] = iou; ia[k] = g; }
        }
    }

    // ---- per-slot epilogue: fixmap, CE (cls loaded here), fg enqueue ----
    float4 cvk[MAXSLOTS];
#pragma unroll
    for (int k = 0; k < MAXSLOTS; ++k) {
        const int araw = (c0 + k * CB) * CHK + tid;
        const int ae = araw < A_TOTAL ? araw : (A_TOTAL - 1);
        cvk[k] = *(const float4*)(cls + (bbase + ae) * NC);
    }
    float sum_ce = 0.f, sum_act = 0.f, sum_fg = 0.f, sum_2d = 0.f, sum_3d = 0.f;
#pragma unroll
    for (int k = 0; k < MAXSLOTS; ++k) {
        const bool live = ((c0 + k * CB) * CHK + tid) < A_TOTAL;
        const float best = m[k];
        int agt = ia[k];
        bool fg = best >= 0.5f;
        const int f = fixmap[k * BLK + tid];
        if (f >= 0) {
            if (f & 0x40000000) fg = true;
            const int code = f & 63;
            agt = (code == 32) ? agt : code;
        }
        if (!live) fg = false; // dead slots/tail lanes contribute nothing
        const bool bgm = live && (!fg) && (best < 0.5f) && (best >= 0.0f);
        const float active = (fg || bgm) ? 1.f : 0.f;
        const int lbl = fg ? lbl_s[agt] : 0;

        const float4 c4 = cvk[k];
        const float mx = fmaxf(fmaxf(c4.x, c4.y), fmaxf(c4.z, c4.w));
        const float se = __expf(c4.x - mx) + __expf(c4.y - mx) +
                         __expf(c4.z - mx) + __expf(c4.w - mx);
        const float lse = mx + __logf(se);
        const float csel = (lbl == 0) ? c4.x : (lbl == 1) ? c4.y
                         : (lbl == 2) ? c4.z : c4.w;
        sum_ce += (lse - csel) * active;
        sum_act += active;

        if (fg) { // rare: enqueue {slot,tid,agt}; regression runs below
            sum_fg += 1.f;
            const int p = atomicAdd(&nloc, 1); // capacity == block anchor count
            fglist[p] = ((unsigned)k << 14) | ((unsigned)tid << 5) | (unsigned)agt;
        }
    }

    // ---- fg regression epilogue (identical per-anchor float math) ----
    __syncthreads(); // all appends visible, nloc final
    const int nfgl = nloc;
    for (int i = tid; i < nfgl; i += BLK) {
        const unsigned e = fglist[i];
        const int k2 = (int)(e >> 14);
        const int tid2 = (int)((e >> 5) & 511u);
        const int agt = (int)(e & 31u);
        const int a = (c0 + k2 * CB) * CHK + tid2;
        const int t = a % NANC;
        const int cell = a / NANC;
        const float sx = (float)((cell % FEAT_W) * STRIDEPX);
        const float sy = (float)((cell / FEAT_W) * STRIDEPX);
        const float r0 = sx + ax0_s[t], r1 = sy + ay0_s[t];
        const float r2 = sx + ax1_s[t], r3 = sy + ay1_s[t];
        const float w = r2 - r0 + 1.f, h = r3 - r1 + 1.f;
        const float rw = __builtin_amdgcn_rcpf(w);
        const float rh = __builtin_amdgcn_rcpf(h);
        const float cx = r0 + 0.5f * w, cy = r1 + 0.5f * h;
        const float4 Gq = gtb4_s[agt];
        const float gw = Gq.z - Gq.x + 1.f, gh = Gq.w - Gq.y + 1.f;
        const float gcx = Gq.x + 0.5f * gw, gcy = Gq.y + 0.5f * gh;
        float tt2[4];
        tt2[0] = (gcx - cx) * rw;
        tt2[1] = (gcy - cy) * rh;
        tt2[2] = __logf(gw * rw);
        tt2[3] = __logf(gh * rh);
        const float4 b2 = *(const float4*)(bbox_2d + (bbase + a) * 4);
        const float b2v[4] = {b2.x, b2.y, b2.z, b2.w};
        float l2 = 0.f;
        for (int j = 0; j < 4; ++j)
            l2 += smooth_l1(b2v[j] - (tt2[j] - mean_s[j]) * rstd_s[j]);
        sum_2d += l2;
        const float* q3p = &gt3_s[agt * 7];
        const float* b3 = bbox_3d + (bbase + a) * 7;
        float tt3[7];
        tt3[0] = (q3p[0] - cx) * rw;
        tt3[1] = (q3p[1] - cy) * rh;
        tt3[2] = q3p[2] - anch9[t * 9 + 4];
        tt3[3] = __logf(q3p[3] * __builtin_amdgcn_rcpf(anch9[t * 9 + 5]));
        tt3[4] = __logf(q3p[4] * __builtin_amdgcn_rcpf(anch9[t * 9 + 6]));
        tt3[5] = __logf(q3p[5] * __builtin_amdgcn_rcpf(anch9[t * 9 + 7]));
        tt3[6] = q3p[6] - anch9[t * 9 + 8];
        float l3 = 0.f;
        for (int j = 0; j < 7; ++j)
            l3 += smooth_l1(b3[j] - (tt3[j] - mean_s[4 + j]) * rstd_s[4 + j]);
        sum_3d += l3;
    }

    // ---- block reduce -> 5 atomics; last block finishes ----
    float vals[5] = {sum_ce, sum_act, sum_fg, sum_2d, sum_3d};
#pragma unroll
    for (int j = 0; j < 5; ++j) {
        float v = vals[j];
        for (int off = 32; off; off >>= 1) v += __shfl_down(v, off, 64);
        if ((tid & 63) == 0) red[j][tid >> 6] = v;
    }
    __syncthreads();
    if (tid == 0) {
        for (int j = 0; j < 5; ++j) {
            float s = 0.f;
            for (int w = 0; w < BLK / 64; ++w) s += red[j][w];
            atomicAdd(&acc[j], s);
        }
        __threadfence();
        const unsigned old = atomicAdd(done, 1u);
        if (old == G2 - 1) {
            const float a0 = atomicAdd(&acc[0], 0.f);
            const float a1 = atomicAdd(&acc[1], 0.f);
            const float a2 = atomicAdd(&acc[2], 0.f);
            const float a3 = atomicAdd(&acc[3], 0.f);
            const float a4 = atomicAdd(&acc[4], 0.f);
            const float nact = fmaxf(a1, 1.f);
            const float nfg = fmaxf(a2, 1.f);
            out[0] = a0 / nact + a3 / nfg + a4 / nfg;
        }
    }
}

extern "C" void kernel_launch(void* const* d_in, const int* in_sizes, int n_in,
                              void* d_out, int out_size, void* d_ws, size_t ws_size,
                              hipStream_t stream) {
    const float* cls      = (const float*)d_in[0];
    const float* bbox_2d  = (const float*)d_in[1];
    const float* bbox_3d  = (const float*)d_in[2];
    const float* gt_boxes = (const float*)d_in[3];
    const float* gt_3d    = (const float*)d_in[4];
    const int*   gt_labels= (const int*)d_in[5];
    const int*   gt_valid = (const int*)d_in[6];
    const float* anchors  = (const float*)d_in[7];
    const float* means    = (const float*)d_in[8];
    const float* stds     = (const float*)d_in[9];

    unsigned long long* colpart = (unsigned long long*)d_ws;  // 2 KB @0
    float* acc = (float*)((char*)d_ws + 8192);
    unsigned* done = (unsigned*)((char*)d_ws + 8192 + 32);
    float* out = (float*)d_out;

    k_colpass<<<NB * NG, CPB, 0, stream>>>(gt_boxes, gt_valid, anchors,
                                           colpart, acc, done);
    k_main<<<G2, BLK, 0, stream>>>(cls, bbox_2d, bbox_3d, gt_boxes, gt_3d,
                                   gt_labels, gt_valid, anchors, means, stds,
                                   colpart, acc, done, out);
}